// Round 8
// baseline (9701.954 us; speedup 1.0000x reference)
//
#include <hip/hip_runtime.h>
#include <hip/hip_bf16.h>
#include <math.h>

#define Bb 64
#define Tt 512
#define Dd 1024
#define Uu 1024
#define NWG 64       // persistent workgroups (1 per CU, trivially co-resident)
#define NTHR 512     // 8 waves: 0-3 h-GEMM (K=256 each), 4-7 x-GEMM (K=256 each)
#define UPW 16       // u's per WG
#define NCOL 64      // packed cols per WG = 4 gates * 16 u
#define KTOT 2048    // D + U packed K
#define ZP 66        // zbuf row stride (f32): (2r+c)%32 banks -> <=2-way

#define BUF_FLOATS (64 * ZP)
#define DYN_LDS (6 * BUF_FLOATS * 4)  // 0 zhA, 1 zhB, 2 zxA0, 3 zxB0, 4 zxA1, 5 zxB1

typedef __attribute__((ext_vector_type(8))) short bf16x8;
typedef __attribute__((ext_vector_type(4))) float f32x4;
typedef __attribute__((ext_vector_type(2))) float f32x2;

// ---- one-time prep -------------------------------------------------------

__global__ void cast_x_bf16(const float* __restrict__ in, __hip_bfloat16* __restrict__ out, int n4) {
  int i = blockIdx.x * blockDim.x + threadIdx.x;
  int stride = gridDim.x * blockDim.x;
  for (; i < n4; i += stride) {
    float4 v = reinterpret_cast<const float4*>(in)[i];
    __hip_bfloat16* o = out + 4 * (size_t)i;
    o[0] = __float2bfloat16(v.x);
    o[1] = __float2bfloat16(v.y);
    o[2] = __float2bfloat16(v.z);
    o[3] = __float2bfloat16(v.w);
  }
}

// in: fp32 [1024][4096]. out packed bf16: pWT[(j*64 + pc)*2048 + koff + k],
// col = g*1024 + j*16 + uu  ->  j = (col&1023)>>4, pc = g*16 + uu.
__global__ void pack_w(const float* __restrict__ in, __hip_bfloat16* __restrict__ pWT, int koff) {
  __shared__ float tile[32][33];
  int n0 = blockIdx.x * 32, k0 = blockIdx.y * 32;
  int tx = threadIdx.x, ty = threadIdx.y;
#pragma unroll
  for (int p = 0; p < 4; ++p) {
    int r = ty + p * 8;
    tile[r][tx] = in[(size_t)(k0 + r) * (4 * Uu) + n0 + tx];
  }
  __syncthreads();
#pragma unroll
  for (int p = 0; p < 4; ++p) {
    int r = ty + p * 8;
    int col = n0 + r;
    int j = (col & (Uu - 1)) >> 4;
    int g = col >> 10;
    int uu = col & 15;
    pWT[((size_t)(j * NCOL + g * 16 + uu)) * KTOT + koff + k0 + tx] = __float2bfloat16(tile[tx][r]);
  }
}

// ---- helpers ---------------------------------------------------------------

__device__ __forceinline__ unsigned pollSys(const unsigned* p) {
  return __hip_atomic_load(p, __ATOMIC_RELAXED, __HIP_MEMORY_SCOPE_SYSTEM);
}

#define WAITV(n)                                             \
  do {                                                       \
    asm volatile("s_waitcnt vmcnt(" #n ")" ::: "memory");    \
    __builtin_amdgcn_sched_barrier(0);                       \
  } while (0)

// B-fragments (weights, immutable -> plain cached 16B loads)
#define ISSUE_B2(arr, kkb)                                                     \
  {                                                                            \
    _Pragma("unroll") for (int kkr = 0; kkr < 2; ++kkr) {                      \
      _Pragma("unroll") for (int ct = 0; ct < 4; ++ct) {                       \
        asm volatile("global_load_dwordx4 %0, %1, off offset:%2"               \
                     : "=v"(arr[kkr * 4 + ct])                                 \
                     : "v"(baddr[ct]), "i"((((kkb) + kkr) * 64))               \
                     : "memory");                                              \
      }                                                                        \
    }                                                                          \
  }

// A-fragments, h (cross-XCD coherent -> sc0 sc1 16B loads)
#define ISSUE_AH2(arr, kkb)                                                    \
  {                                                                            \
    _Pragma("unroll") for (int kkr = 0; kkr < 2; ++kkr) {                      \
      _Pragma("unroll") for (int mt = 0; mt < 4; ++mt) {                       \
        asm volatile("global_load_dwordx4 %0, %1, off offset:%2 sc0 sc1"       \
                     : "=v"(arr[kkr * 4 + mt])                                 \
                     : "v"(haddr[mt]), "i"((((kkb) + kkr) * 64))               \
                     : "memory");                                              \
      }                                                                        \
    }                                                                          \
  }

// A-fragments, x (immutable -> plain 16B loads)
#define ISSUE_AX2(arr, kkb)                                                    \
  {                                                                            \
    _Pragma("unroll") for (int kkr = 0; kkr < 2; ++kkr) {                      \
      _Pragma("unroll") for (int mt = 0; mt < 4; ++mt) {                       \
        asm volatile("global_load_dwordx4 %0, %1, off offset:%2"               \
                     : "=v"(arr[kkr * 4 + mt])                                 \
                     : "v"(xaddr[mt]), "i"((((kkb) + kkr) * 64))               \
                     : "memory");                                              \
      }                                                                        \
    }                                                                          \
  }

#define MFMA2B(aarr, barr)                                                     \
  {                                                                            \
    _Pragma("unroll") for (int kkr = 0; kkr < 2; ++kkr) {                      \
      _Pragma("unroll") for (int mt = 0; mt < 4; ++mt) {                       \
        _Pragma("unroll") for (int ct = 0; ct < 4; ++ct) {                     \
          acc[mt][ct] = __builtin_amdgcn_mfma_f32_16x16x32_bf16(               \
              __builtin_bit_cast(bf16x8, aarr[kkr * 4 + mt]),                  \
              __builtin_bit_cast(bf16x8, barr[kkr * 4 + ct]),                  \
              acc[mt][ct], 0, 0, 0);                                           \
        }                                                                      \
      }                                                                        \
    }                                                                          \
  }

#define ZERO_ACC                                                               \
  {                                                                            \
    _Pragma("unroll") for (int mt = 0; mt < 4; ++mt)                           \
      _Pragma("unroll") for (int ct = 0; ct < 4; ++ct)                         \
        acc[mt][ct] = (f32x4){0.f, 0.f, 0.f, 0.f};                             \
  }

// C/D layout: col = lane&15, row = (lane>>4)*4 + q  [m89/m91]
#define ZWRITE(bufp)                                                           \
  {                                                                            \
    float* _b = (bufp);                                                        \
    _Pragma("unroll") for (int mt = 0; mt < 4; ++mt)                           \
      _Pragma("unroll") for (int ct = 0; ct < 4; ++ct)                         \
        _Pragma("unroll") for (int q = 0; q < 4; ++q)                          \
          _b[(mt * 16 + lk * 4 + q) * ZP + ct * 16 + l15] = acc[mt][ct][q];    \
  }

#define ZRMW(bufp)                                                             \
  {                                                                            \
    float* _b = (bufp);                                                        \
    _Pragma("unroll") for (int mt = 0; mt < 4; ++mt)                           \
      _Pragma("unroll") for (int ct = 0; ct < 4; ++ct)                         \
        _Pragma("unroll") for (int q = 0; q < 4; ++q)                          \
          _b[(mt * 16 + lk * 4 + q) * ZP + ct * 16 + l15] += acc[mt][ct][q];   \
  }

// 2-deep counted-vmcnt ladder over kk = 0..7 (K=256 per wave)
#define LADDER(AISSUE)                                                         \
  AISSUE(a0, 0);                                                               \
  AISSUE(a1, 2);                                                               \
  WAITV(8);                                                                    \
  MFMA2B(a0, b0);                                                              \
  ISSUE_B2(b0, 4);                                                             \
  AISSUE(a0, 4);                                                               \
  WAITV(16);                                                                   \
  MFMA2B(a1, b1);                                                              \
  ISSUE_B2(b1, 6);                                                             \
  AISSUE(a1, 6);                                                               \
  WAITV(16);                                                                   \
  MFMA2B(a0, b0);                                                              \
  WAITV(0);                                                                    \
  MFMA2B(a1, b1);

// ---- persistent LSTM -------------------------------------------------------
// 64 WGs x 512 thr. WG j owns u in [j*16, j*16+16) -> 64 cols (4 gates).
// Waves 0-3: zh(t) over K-slice wv*256 (h via sc loads after release).
// Waves 4-7: zx(t+1) over K-slice (wv-4)*256 (plain loads, off critical path).
// Partials: writer wave stores, partner wave RMWs after mid-sync.
// Sync: 64 flags -> WG0.wv0 aggregates -> 16 rel replicas -> per-WG LDS gate.
__launch_bounds__(NTHR, 2)
__global__ void lstm_persist(const __hip_bfloat16* __restrict__ xb,
                             const __hip_bfloat16* __restrict__ pWT,
                             const float* __restrict__ bias,
                             const float* __restrict__ h0,
                             const float* __restrict__ c0,
                             __hip_bfloat16* __restrict__ hb,  // [2][B][U]
                             float* __restrict__ out,
                             unsigned* __restrict__ flags,     // [NWG][16] 64B lines
                             unsigned* __restrict__ rel) {     // [16][16] replicas
  extern __shared__ __align__(16) float zbuf[];
  __shared__ unsigned gate;

  const int tid = threadIdx.x;
  const int wv = tid >> 6;
  const int lane = tid & 63;
  const int l15 = lane & 15;
  const int lk = lane >> 4;
  const int j = blockIdx.x;

  if (tid == 0) gate = 0;

  const bool isH = (wv < 4);
  const int ks = isH ? wv : (wv - 4);  // K-slice (256-wide)

  // B-frag bases (constant over t): pWT[(j*64 + ct*16 + l15)*2048 + kbase + lk*8]
  unsigned long long baddr[4];
#pragma unroll
  for (int ct = 0; ct < 4; ++ct)
    baddr[ct] = (unsigned long long)(pWT + ((size_t)j * NCOL + ct * 16 + l15) * KTOT +
                                     (isH ? Dd : 0) + ks * 256) +
                (unsigned long long)lk * 16;

  // x A-frag bases at t=0; advance 2048B/step
  unsigned long long xaddr[4];
#pragma unroll
  for (int mt = 0; mt < 4; ++mt)
    xaddr[mt] = (unsigned long long)(xb + (size_t)(mt * 16 + l15) * Tt * Dd + ks * 256) +
                (unsigned long long)lk * 16;

  // epilogue state: one batch row, two adjacent u's
  const int eb = tid & 63;
  const int ug = tid >> 6;  // 0..7
  const int u0 = j * UPW + ug * 2;
  float bi[4][2];
#pragma unroll
  for (int g = 0; g < 4; ++g) {
    bi[g][0] = bias[g * Uu + u0];
    bi[g][1] = bias[g * Uu + u0 + 1];
  }
  float cr0 = c0[(size_t)eb * Uu + u0];
  float cr1 = c0[(size_t)eb * Uu + u0 + 1];

  unsigned* hb32 = (unsigned*)hb;
  {
    union { __hip_bfloat162 v; unsigned u; } pk;
    pk.v.x = __float2bfloat16(h0[(size_t)eb * Uu + u0]);
    pk.v.y = __float2bfloat16(h0[(size_t)eb * Uu + u0 + 1]);
    __hip_atomic_store(&hb32[((size_t)eb * Uu + u0) >> 1], pk.u,
                       __ATOMIC_RELAXED, __HIP_MEMORY_SCOPE_SYSTEM);
  }

  f32x4 a0[8], a1[8], b0[8], b1[8];
  f32x4 acc[4][4];

  // drain init loads/stores so manual vmcnt counts start from 0
  WAITV(0);

  // ---- prologue: zx(0) by x-waves into bufs 2,3 ----
  if (!isH) {
    ZERO_ACC;
    ISSUE_B2(b0, 0);
    ISSUE_B2(b1, 2);
    LADDER(ISSUE_AX2);
    if (wv == 4) ZWRITE(zbuf + 2 * BUF_FLOATS);
    if (wv == 6) ZWRITE(zbuf + 3 * BUF_FLOATS);
  }
  __syncthreads();
  if (wv == 5) ZRMW(zbuf + 2 * BUF_FLOATS);
  if (wv == 7) ZRMW(zbuf + 3 * BUF_FLOATS);

  for (int t = 0; t < Tt; ++t) {
    // joins epilogue(t-1)/RMWs; drains vmcnt -> h(t) sc-stores ack'd at MALL
    __syncthreads();

    const unsigned want = (unsigned)(t + 1);
    if (tid == 0)
      __hip_atomic_store(&flags[j * 16], want, __ATOMIC_RELAXED, __HIP_MEMORY_SCOPE_SYSTEM);

    ZERO_ACC;

    if (isH) {
      const __hip_bfloat16* hcur = hb + (size_t)(t & 1) * (Bb * Uu);
      unsigned long long haddr[4];
#pragma unroll
      for (int mt = 0; mt < 4; ++mt)
        haddr[mt] = (unsigned long long)(hcur + (size_t)(mt * 16 + l15) * Uu + ks * 256) +
                    (unsigned long long)lk * 16;

      // weight loads: legal before release (immutable), hidden under the wait
      ISSUE_B2(b0, 0);
      ISSUE_B2(b1, 2);

      // ---- sync: flags -> aggregator -> rel replicas -> LDS gate
      if (wv == 0) {
        if (j == 0) {
          while (pollSys(&flags[lane * 16]) < want) __builtin_amdgcn_s_sleep(1);
          if (lane < 16)
            __hip_atomic_store(&rel[lane * 16], want, __ATOMIC_RELAXED,
                               __HIP_MEMORY_SCOPE_SYSTEM);
        } else {
          if (lane == 0)
            while (pollSys(&rel[(j & 15) * 16]) < want) __builtin_amdgcn_s_sleep(1);
        }
        if (lane == 0)
          __hip_atomic_store(&gate, want, __ATOMIC_RELAXED, __HIP_MEMORY_SCOPE_WORKGROUP);
      } else {
        while (__hip_atomic_load(&gate, __ATOMIC_RELAXED, __HIP_MEMORY_SCOPE_WORKGROUP) < want)
          __builtin_amdgcn_s_sleep(1);
      }
      __builtin_amdgcn_sched_barrier(0);

      LADDER(ISSUE_AH2);

      if (wv == 0) ZWRITE(zbuf);
      if (wv == 2) ZWRITE(zbuf + BUF_FLOATS);
    } else {
      // ---- x part for step t+1 (no dependency; overlaps the h-side wait)
      if (t + 1 < Tt) {
#pragma unroll
        for (int mt = 0; mt < 4; ++mt) xaddr[mt] += 2048;
      }
      ISSUE_B2(b0, 0);
      ISSUE_B2(b1, 2);
      LADDER(ISSUE_AX2);

      const int pn = (t + 1) & 1;
      if (wv == 4) ZWRITE(zbuf + (2 + 2 * pn) * BUF_FLOATS);
      if (wv == 6) ZWRITE(zbuf + (3 + 2 * pn) * BUF_FLOATS);
    }

    __syncthreads();  // writers done -> RMW partners add

    if (wv == 1) ZRMW(zbuf);
    if (wv == 3) ZRMW(zbuf + BUF_FLOATS);
    if (!isH) {
      const int pn = (t + 1) & 1;
      if (wv == 5) ZRMW(zbuf + (2 + 2 * pn) * BUF_FLOATS);
      if (wv == 7) ZRMW(zbuf + (3 + 2 * pn) * BUF_FLOATS);
    }

    __syncthreads();  // partials final -> epilogue

    // ---- epilogue(t): z = zhA+zhB+zxA(t)+zxB(t)+bias; gates; emit
    const float* zhA = zbuf;
    const float* zhB = zbuf + BUF_FLOATS;
    const float* zxA = zbuf + (2 + 2 * (t & 1)) * BUF_FLOATS;
    const float* zxB = zbuf + (3 + 2 * (t & 1)) * BUF_FLOATS;
    unsigned* hnxt32 = hb32 + ((size_t)((t + 1) & 1) * (Bb * Uu) >> 1);

    float zz[4][2];
#pragma unroll
    for (int g = 0; g < 4; ++g) {
      const int idx = eb * ZP + g * 16 + ug * 2;
      f32x2 s = *(const f32x2*)&zhA[idx];
      f32x2 v1 = *(const f32x2*)&zhB[idx];
      f32x2 v2 = *(const f32x2*)&zxA[idx];
      f32x2 v3 = *(const f32x2*)&zxB[idx];
      zz[g][0] = s.x + v1.x + v2.x + v3.x + bi[g][0];
      zz[g][1] = s.y + v1.y + v2.y + v3.y + bi[g][1];
    }
    float hv0, hv1;
    {
      float ig = 1.f / (1.f + __expf(-zz[0][0]));
      float fg = 1.f / (1.f + __expf(-zz[1][0]));
      float gg = tanhf(zz[2][0]);
      float og = 1.f / (1.f + __expf(-zz[3][0]));
      cr0 = fg * cr0 + ig * gg;
      hv0 = og * tanhf(cr0);
    }
    {
      float ig = 1.f / (1.f + __expf(-zz[0][1]));
      float fg = 1.f / (1.f + __expf(-zz[1][1]));
      float gg = tanhf(zz[2][1]);
      float og = 1.f / (1.f + __expf(-zz[3][1]));
      cr1 = fg * cr1 + ig * gg;
      hv1 = og * tanhf(cr1);
    }
    f32x2 o2 = {hv0, hv1};
    __builtin_nontemporal_store(o2, (f32x2*)(out + ((size_t)eb * Tt + t) * Uu + u0));
    {
      union { __hip_bfloat162 v; unsigned u; } pk;
      pk.v.x = __float2bfloat16(hv0);
      pk.v.y = __float2bfloat16(hv1);
      __hip_atomic_store(&hnxt32[((size_t)eb * Uu + u0) >> 1], pk.u,
                         __ATOMIC_RELAXED, __HIP_MEMORY_SCOPE_SYSTEM);
    }
  }
}

// ---- launch --------------------------------------------------------------

extern "C" void kernel_launch(void* const* d_in, const int* in_sizes, int n_in,
                              void* d_out, int out_size, void* d_ws, size_t ws_size,
                              hipStream_t stream) {
  const float* x = (const float*)d_in[0];
  const float* h0 = (const float*)d_in[1];
  const float* c0 = (const float*)d_in[2];
  const float* Wx = (const float*)d_in[3];
  const float* Wh = (const float*)d_in[4];
  const float* bias = (const float*)d_in[5];
  float* out = (float*)d_out;

  char* ws = (char*)d_ws;
  size_t off = 0;
  __hip_bfloat16* xb = (__hip_bfloat16*)(ws + off);  off += (size_t)Bb * Tt * Dd * 2;       // 64 MB
  __hip_bfloat16* pWT = (__hip_bfloat16*)(ws + off); off += (size_t)NWG * NCOL * KTOT * 2;  // 16 MB
  __hip_bfloat16* hb = (__hip_bfloat16*)(ws + off);  off += (size_t)2 * Bb * Uu * 2;        // 256 KB
  unsigned* flags = (unsigned*)(ws + off);           off += (size_t)NWG * 64;               // 4 KB
  unsigned* rel = (unsigned*)(ws + off);             off += (size_t)16 * 64;                // 1 KB

  hipFuncSetAttribute((const void*)lstm_persist,
                      hipFuncAttributeMaxDynamicSharedMemorySize, DYN_LDS);

  cast_x_bf16<<<4096, 256, 0, stream>>>(x, xb, Bb * Tt * Dd / 4);
  pack_w<<<dim3(4 * Uu / 32, Dd / 32), dim3(32, 8), 0, stream>>>(Wx, pWT, 0);
  pack_w<<<dim3(4 * Uu / 32, Uu / 32), dim3(32, 8), 0, stream>>>(Wh, pWT, Dd);
  hipMemsetAsync(flags, 0, (size_t)NWG * 64 + 16 * 64, stream);

  lstm_persist<<<NWG, NTHR, DYN_LDS, stream>>>(xb, pWT, bias, h0, c0, hb, out, flags, rel);
}